// Round 9
// baseline (1461.752 us; speedup 1.0000x reference)
//
#include <hip/hip_runtime.h>
#include <hip/hip_bf16.h>
#include <stdint.h>

#define HID  4096
#define INTR 14336
#define GS   64
#define TOK  4096
#define GRP1 (HID / GS)
#define GRP2 (INTR / GS)

#define BK 64

typedef __attribute__((ext_vector_type(8))) short short8;  // 8 bf16
typedef __attribute__((ext_vector_type(4))) float f32x4;   // 16x16 MFMA acc
typedef unsigned short u16;
typedef unsigned int   u32;

// ---- helpers -------------------------------------------------------------

__device__ __forceinline__ u16 f2b(float x) {
    return __builtin_bit_cast(u16, __float2bfloat16(x));
}
__device__ __forceinline__ u32 pk2(float a, float b) {
    return (u32)f2b(a) | ((u32)f2b(b) << 16);
}
__device__ __forceinline__ u32 dq2(int ca, int cb, float s, float off) {
    return pk2(fmaf((float)ca, s, off), fmaf((float)cb, s, off));
}
__device__ __forceinline__ uint4 dqw(u32 w, float s, float off) {
    uint4 v;
    v.x = dq2((int)( w        & 15), (int)((w >>  4) & 15), s, off);
    v.y = dq2((int)((w >>  8) & 15), (int)((w >> 12) & 15), s, off);
    v.z = dq2((int)((w >> 16) & 15), (int)((w >> 20) & 15), s, off);
    v.w = dq2((int)((w >> 24) & 15), (int)( w >> 28       ), s, off);
    return v;
}
__device__ __forceinline__ void gload16(const void* g, void* l) {
    __builtin_amdgcn_global_load_lds(
        (const __attribute__((address_space(1))) void*)g,
        (__attribute__((address_space(3))) void*)l, 16, 0, 0);
}
__device__ __forceinline__ void vmcnt4() {
    asm volatile("s_waitcnt vmcnt(4)" ::: "memory");
}
__device__ __forceinline__ void lgkm0() {
    asm volatile("s_waitcnt lgkmcnt(0)" ::: "memory");
    __builtin_amdgcn_sched_barrier(0);
}
#define BAR() __builtin_amdgcn_s_barrier()

// ---- weight dequant: int32 codes -> bf16, 4-chunk PRE-SWIZZLE -------------
// position = (c & ~3) | ((c&3) ^ (r&3))  (XOR within each 32-elem K-half)

__global__ void dqw_kernel(const int* __restrict__ q, const float* __restrict__ s,
                           const float* __restrict__ z, u16* __restrict__ o, int cols) {
    int c = blockIdx.x * blockDim.x + threadIdx.x;   // 8-elem chunk in row
    int r = blockIdx.y;
    int grp = cols >> 6;
    const int* src = q + (size_t)r * cols + ((size_t)c << 3);
    int4 a = *(const int4*)src;
    int4 b = *(const int4*)(src + 4);
    float sc = s[(size_t)r * grp + (c >> 3)];
    float zz = z[(size_t)r * grp + (c >> 3)];
    float of = -zz * sc;
    uint4 v;
    v.x = dq2(a.x, a.y, sc, of);
    v.y = dq2(a.z, a.w, sc, of);
    v.z = dq2(b.x, b.y, sc, of);
    v.w = dq2(b.z, b.w, sc, of);
    int cs = (c & ~3) | ((c & 3) ^ (r & 3));
    *(uint4*)(o + (size_t)r * cols + ((size_t)cs << 3)) = v;
}

// ---- repack (fallback): int32 -> 8x 4-bit nibbles per u32 -----------------

__global__ void pack_kernel(const int* __restrict__ q, u32* __restrict__ p) {
    int i = blockIdx.x * blockDim.x + threadIdx.x;
    const int4* s = (const int4*)q + (size_t)i * 2;
    int4 a = s[0], b = s[1];
    u32 w = (u32)(a.x & 15)        | ((u32)(a.y & 15) << 4)
          | ((u32)(a.z & 15) << 8) | ((u32)(a.w & 15) << 12)
          | ((u32)(b.x & 15) << 16)| ((u32)(b.y & 15) << 20)
          | ((u32)(b.z & 15) << 24)| ((u32)(b.w & 15) << 28);
    p[i] = w;
}

// ---- hs fp32 -> bf16, 4-chunk PRE-SWIZZLE ---------------------------------

__global__ void cvt_hs_kernel(const float* __restrict__ x, u16* __restrict__ y) {
    int i = blockIdx.x * blockDim.x + threadIdx.x;
    int t = i >> 9;
    int c = i & 511;
    const float4* xp = (const float4*)x + (size_t)i * 2;
    float4 a = xp[0], b = xp[1];
    uint4 o;
    o.x = pk2(a.x, a.y); o.y = pk2(a.z, a.w);
    o.z = pk2(b.x, b.y); o.w = pk2(b.z, b.w);
    int cs = (c & ~3) | ((c & 3) ^ (t & 3));
    ((uint4*)y)[(size_t)t * 512 + cs] = o;
}

// ---- kernel 2: fused gate+up dual GEMM + SiLU*mul -------------------------
// BM=256 BN=128 BK=64, 8 waves (4Mx2N), wave tile 64x64, 16x16x32 MFMA.
// LDS per buffer: A[2][256][32] 32K | B1[2][128][32] 16K | B3 16K. Dbuf 128K.
// MODE 0: 4-phase counted-vmcnt schedule (T2+T3+T4+T5). MODE 1: simple loop.

template<int MODE>
__global__ __launch_bounds__(512) void gateup_kernel(
    const u16* __restrict__ hsb,
    const u16* __restrict__ w1b, const u16* __restrict__ w3b,
    const u32* __restrict__ w1p, const u32* __restrict__ w3p,
    const float* __restrict__ s1, const float* __restrict__ z1,
    const float* __restrict__ s3, const float* __restrict__ z3,
    u16* __restrict__ hout)
{
    __shared__ __align__(16) char smem[131072];

    const int tid  = threadIdx.x;
    const int row0 = blockIdx.x * 256;
    const int col0 = blockIdx.y * 128;

    const int l   = tid & 63;
    const int wid = tid >> 6;
    const int wr  = wid >> 1;
    const int wc  = wid & 1;
    const int fq  = l >> 4;
    const int fr  = l & 15;

    f32x4 accg[4][4];
    f32x4 accu[4][4];
#pragma unroll
    for (int m = 0; m < 4; ++m)
#pragma unroll
        for (int n = 0; n < 4; ++n) {
            accg[m][n] = (f32x4){0.f, 0.f, 0.f, 0.f};
            accu[m][n] = (f32x4){0.f, 0.f, 0.f, 0.f};
        }

    // DMA sources: lane covers row (l>>2), 16B chunk (l&3) -> 16 rows per 1KB
    const u16* aSrc  = hsb + (size_t)(row0 + (l >> 2)) * HID + ((l & 3) << 3);
    const u16* b1Src = w1b + (size_t)(col0 + (l >> 2)) * HID + ((l & 3) << 3);
    const u16* b3Src = w3b + (size_t)(col0 + (l >> 2)) * HID + ((l & 3) << 3);

    // stage A half h of tile KS into buffer (2 DMAs/thread)
    auto STAGE_A_H = [&](int KS, char* buf, int h) {
        const u16* s = aSrc + KS * 64 + h * 32;
#pragma unroll
        for (int i = 0; i < 2; ++i) {
            int blk = wid * 2 + i;                      // 16 blocks x 16 rows
            gload16(s + (size_t)(blk * 16) * HID, buf + h * 16384 + (blk << 10));
        }
    };
    // stage B1+B3 half h (2 DMAs/thread)
    auto STAGE_B_H = [&](int KS, char* buf, int h) {
        gload16(b1Src + KS * 64 + h * 32 + (size_t)(wid * 16) * HID,
                buf + 32768 + h * 8192 + (wid << 10));
        gload16(b3Src + KS * 64 + h * 32 + (size_t)(wid * 16) * HID,
                buf + 49152 + h * 8192 + (wid << 10));
    };

    const int NK = HID / BK;   // 64

    if constexpr (MODE == 0) {
        // prologue: stage tile 0 (order: Ah0, Bh0, Ah1, Bh1)
        STAGE_A_H(0, smem, 0);
        STAGE_B_H(0, smem, 0);
        STAGE_A_H(0, smem, 1);
        STAGE_B_H(0, smem, 1);
        vmcnt4(); BAR();          // h0(0) ready (h1 may be in flight)

        for (int t = 0; t < NK; ++t) {
            const int cur = t & 1;
            const char* Rb = smem + cur * 65536;
            char* Wb = smem + (cur ^ 1) * 65536;
            const int tn = (t + 1 < NK) ? t + 1 : NK - 1;
            short8 af[4], b1f[4], b3f[4];

            // ---- P1: kk0 A+B1 reads | stage Ah0(t+1) | MFMA g0 ----
#pragma unroll
            for (int m = 0; m < 4; ++m) {
                int row = wr * 64 + m * 16 + fr;
                af[m] = *(const short8*)(Rb + row * 64 + ((fq ^ (row & 3)) << 4));
            }
#pragma unroll
            for (int n = 0; n < 4; ++n) {
                int row = wc * 64 + n * 16 + fr;
                b1f[n] = *(const short8*)(Rb + 32768 + row * 64 + ((fq ^ (row & 3)) << 4));
            }
            STAGE_A_H(tn, Wb, 0);
            BAR(); lgkm0();
            __builtin_amdgcn_s_setprio(1);
#pragma unroll
            for (int m = 0; m < 4; ++m)
#pragma unroll
                for (int n = 0; n < 4; ++n)
                    accg[m][n] = __builtin_amdgcn_mfma_f32_16x16x32_bf16(af[m], b1f[n], accg[m][n], 0, 0, 0);
            __builtin_amdgcn_s_setprio(0);
            BAR();

            // ---- P2: kk0 B3 reads | stage Bh0(t+1) | MFMA u0 | vmcnt(4) ----
#pragma unroll
            for (int n = 0; n < 4; ++n) {
                int row = wc * 64 + n * 16 + fr;
                b3f[n] = *(const short8*)(Rb + 49152 + row * 64 + ((fq ^ (row & 3)) << 4));
            }
            STAGE_B_H(tn, Wb, 0);
            BAR(); lgkm0();
            __builtin_amdgcn_s_setprio(1);
#pragma unroll
            for (int m = 0; m < 4; ++m)
#pragma unroll
                for (int n = 0; n < 4; ++n)
                    accu[m][n] = __builtin_amdgcn_mfma_f32_16x16x32_bf16(af[m], b3f[n], accu[m][n], 0, 0, 0);
            __builtin_amdgcn_s_setprio(0);
            vmcnt4(); BAR();      // h1(t) ready

            // ---- P3: kk1 A+B1 reads | stage Ah1(t+1) | MFMA g1 ----
#pragma unroll
            for (int m = 0; m < 4; ++m) {
                int row = wr * 64 + m * 16 + fr;
                af[m] = *(const short8*)(Rb + 16384 + row * 64 + ((fq ^ (row & 3)) << 4));
            }
#pragma unroll
            for (int n = 0; n < 4; ++n) {
                int row = wc * 64 + n * 16 + fr;
                b1f[n] = *(const short8*)(Rb + 40960 + row * 64 + ((fq ^ (row & 3)) << 4));
            }
            STAGE_A_H(tn, Wb, 1);
            BAR(); lgkm0();
            __builtin_amdgcn_s_setprio(1);
#pragma unroll
            for (int m = 0; m < 4; ++m)
#pragma unroll
                for (int n = 0; n < 4; ++n)
                    accg[m][n] = __builtin_amdgcn_mfma_f32_16x16x32_bf16(af[m], b1f[n], accg[m][n], 0, 0, 0);
            __builtin_amdgcn_s_setprio(0);
            BAR();

            // ---- P4: kk1 B3 reads | stage Bh1(t+1) | MFMA u1 | vmcnt(4) ----
#pragma unroll
            for (int n = 0; n < 4; ++n) {
                int row = wc * 64 + n * 16 + fr;
                b3f[n] = *(const short8*)(Rb + 57344 + row * 64 + ((fq ^ (row & 3)) << 4));
            }
            STAGE_B_H(tn, Wb, 1);
            BAR(); lgkm0();
            __builtin_amdgcn_s_setprio(1);
#pragma unroll
            for (int m = 0; m < 4; ++m)
#pragma unroll
                for (int n = 0; n < 4; ++n)
                    accu[m][n] = __builtin_amdgcn_mfma_f32_16x16x32_bf16(af[m], b3f[n], accu[m][n], 0, 0, 0);
            __builtin_amdgcn_s_setprio(0);
            vmcnt4(); BAR();      // h0(t+1) ready
        }
        asm volatile("s_waitcnt vmcnt(0)" ::: "memory");
        __syncthreads();
    } else {
        // MODE 1 fallback: packed nibbles, simple double-buffer loop
        const int br  = tid >> 2;              // B row 0..127
        const int bc  = tid & 3;               // chunks 2bc, 2bc+1 (half bc>>1)
        const u32* pp1 = w1p + (size_t)(col0 + br) * (HID / 8) + (bc << 1);
        const u32* pp3 = w3p + (size_t)(col0 + br) * (HID / 8) + (bc << 1);
        const size_t sBase = (size_t)(col0 + br) * GRP1;
        uint2 g1, g3;
        float sc1, zz1, sc3, zz3;

        auto LOADB = [&](int KS) {
            g1 = *(const uint2*)(pp1 + KS * 8);
            g3 = *(const uint2*)(pp3 + KS * 8);
            sc1 = s1[sBase + KS]; zz1 = z1[sBase + KS];
            sc3 = s3[sBase + KS]; zz3 = z3[sBase + KS];
        };
        auto DEQWB = [&](char* buf) {
            u16* dB1 = (u16*)(buf + 32768);
            u16* dB3 = (u16*)(buf + 49152);
            const float of1 = -zz1 * sc1;
            const float of3 = -zz3 * sc3;
            int c0 = bc << 1;
            int p0 = (c0 & 3) ^ (br & 3);
            int p1 = ((c0 + 1) & 3) ^ (br & 3);
            int h  = bc >> 1;
            *(uint4*)(&dB1[h * 4096 + br * 32 + (p0 << 3)]) = dqw(g1.x, sc1, of1);
            *(uint4*)(&dB1[h * 4096 + br * 32 + (p1 << 3)]) = dqw(g1.y, sc1, of1);
            *(uint4*)(&dB3[h * 4096 + br * 32 + (p0 << 3)]) = dqw(g3.x, sc3, of3);
            *(uint4*)(&dB3[h * 4096 + br * 32 + (p1 << 3)]) = dqw(g3.y, sc3, of3);
        };

        LOADB(0);
        STAGE_A_H(0, smem, 0); STAGE_A_H(0, smem, 1);
        DEQWB(smem);
        __syncthreads();
        for (int ks = 0; ks < NK; ++ks) {
            const int nxt = ks + 1 < NK ? ks + 1 : NK - 1;
            const int cur = ks & 1;
            char* Wb = smem + (cur ^ 1) * 65536;
            const char* Rb = smem + cur * 65536;
            LOADB(nxt);
            STAGE_A_H(nxt, Wb, 0); STAGE_A_H(nxt, Wb, 1);
#pragma unroll
            for (int kk = 0; kk < 2; ++kk) {
                short8 af[4], b1f[4], b3f[4];
#pragma unroll
                for (int m = 0; m < 4; ++m) {
                    int row = wr * 64 + m * 16 + fr;
                    af[m] = *(const short8*)(Rb + kk * 16384 + row * 64 + ((fq ^ (row & 3)) << 4));
                }
#pragma unroll
                for (int n = 0; n < 4; ++n) {
                    int row = wc * 64 + n * 16 + fr;
                    int off = row * 64 + ((fq ^ (row & 3)) << 4);
                    b1f[n] = *(const short8*)(Rb + 32768 + kk * 8192 + off);
                    b3f[n] = *(const short8*)(Rb + 49152 + kk * 8192 + off);
                }
#pragma unroll
                for (int m = 0; m < 4; ++m)
#pragma unroll
                    for (int n = 0; n < 4; ++n) {
                        accg[m][n] = __builtin_amdgcn_mfma_f32_16x16x32_bf16(af[m], b1f[n], accg[m][n], 0, 0, 0);
                        accu[m][n] = __builtin_amdgcn_mfma_f32_16x16x32_bf16(af[m], b3f[n], accu[m][n], 0, 0, 0);
                    }
            }
            DEQWB(Wb);
            __syncthreads();
        }
    }

    // -- epilogue: silu(g)*u -> LDS (4-chunk pre-swizzled positions) -> store
    u16* sO = (u16*)smem;    // [256][128] bf16 = 64 KB
#pragma unroll
    for (int m = 0; m < 4; ++m)
#pragma unroll
        for (int n = 0; n < 4; ++n)
#pragma unroll
            for (int r = 0; r < 4; ++r) {
                int lr = wr * 64 + m * 16 + fq * 4 + r;
                int lc = wc * 64 + n * 16 + fr;
                float g = accg[m][n][r];
                float u = accu[m][n][r];
                float hv = (g / (1.0f + __expf(-g))) * u;
                int c  = lc >> 3;
                int cs = (c & ~3) | ((c & 3) ^ (lr & 3));
                sO[lr * 128 + (cs << 3) + (lc & 7)] = f2b(hv);
            }
    __syncthreads();
#pragma unroll
    for (int it = 0; it < 8; ++it) {
        int idx = it * 512 + tid;          // 16B units
        int row = idx >> 4;
        int cu  = idx & 15;
        uint4 v = ((const uint4*)sO)[row * 16 + cu];
        *(uint4*)(&hout[(size_t)(row0 + row) * INTR + col0 + (cu << 3)]) = v;
    }
}

// ---- kernel 3: down proj --------------------------------------------------
// BM=256 BN=256 BK=64, 8 waves (2Mx4N), wave tile 128x64.
// LDS per buffer: A[2][256][32] 32K | B[2][256][32] 32K. Dbuf 128K.

template<int MODE>
__global__ __launch_bounds__(512) void down_kernel(
    const u16* __restrict__ hb,
    const u16* __restrict__ w2b, const u32* __restrict__ w2p,
    const float* __restrict__ s2, const float* __restrict__ z2,
    float* __restrict__ out)
{
    __shared__ __align__(16) char smem[131072];

    const int tid  = threadIdx.x;
    const int row0 = blockIdx.x * 256;
    const int col0 = blockIdx.y * 256;

    const int l   = tid & 63;
    const int wid = tid >> 6;
    const int wr  = wid >> 2;
    const int wc  = wid & 3;
    const int fq  = l >> 4;
    const int fr  = l & 15;

    f32x4 acc[8][4];
#pragma unroll
    for (int m = 0; m < 8; ++m)
#pragma unroll
        for (int n = 0; n < 4; ++n)
            acc[m][n] = (f32x4){0.f, 0.f, 0.f, 0.f};

    const u16* aSrc = hb  + (size_t)(row0 + (l >> 2)) * INTR + ((l & 3) << 3);
    const u16* bSrc = w2b + (size_t)(col0 + (l >> 2)) * INTR + ((l & 3) << 3);

    auto STAGE_A_H = [&](int KS, char* buf, int h) {
        const u16* s = aSrc + KS * 64 + h * 32;
#pragma unroll
        for (int i = 0; i < 2; ++i) {
            int blk = wid * 2 + i;
            gload16(s + (size_t)(blk * 16) * INTR, buf + h * 16384 + (blk << 10));
        }
    };
    auto STAGE_B_H = [&](int KS, char* buf, int h) {
        const u16* s = bSrc + KS * 64 + h * 32;
#pragma unroll
        for (int i = 0; i < 2; ++i) {
            int blk = wid * 2 + i;
            gload16(s + (size_t)(blk * 16) * INTR, buf + 32768 + h * 16384 + (blk << 10));
        }
    };

    const int NK = INTR / BK;   // 224

    if constexpr (MODE == 0) {
        STAGE_A_H(0, smem, 0);
        STAGE_B_H(0, smem, 0);
        STAGE_A_H(0, smem, 1);
        STAGE_B_H(0, smem, 1);
        vmcnt4(); BAR();

        for (int t = 0; t < NK; ++t) {
            const int cur = t & 1;
            const char* Rb = smem + cur * 65536;
            char* Wb = smem + (cur ^ 1) * 65536;
            const int tn = (t + 1 < NK) ? t + 1 : NK - 1;
            short8 af[8], bf[4];

            // ---- P1: kk0 af[0..3]+bf reads | stage Ah0(t+1) | MFMA m0-3 ----
#pragma unroll
            for (int m = 0; m < 4; ++m) {
                int row = wr * 128 + m * 16 + fr;
                af[m] = *(const short8*)(Rb + row * 64 + ((fq ^ (row & 3)) << 4));
            }
#pragma unroll
            for (int n = 0; n < 4; ++n) {
                int row = wc * 64 + n * 16 + fr;
                bf[n] = *(const short8*)(Rb + 32768 + row * 64 + ((fq ^ (row & 3)) << 4));
            }
            STAGE_A_H(tn, Wb, 0);
            BAR(); lgkm0();
            __builtin_amdgcn_s_setprio(1);
#pragma unroll
            for (int m = 0; m < 4; ++m)
#pragma unroll
                for (int n = 0; n < 4; ++n)
                    acc[m][n] = __builtin_amdgcn_mfma_f32_16x16x32_bf16(af[m], bf[n], acc[m][n], 0, 0, 0);
            __builtin_amdgcn_s_setprio(0);
            BAR();

            // ---- P2: kk0 af[4..7] reads | stage Bh0(t+1) | MFMA m4-7 ----
#pragma unroll
            for (int m = 4; m < 8; ++m) {
                int row = wr * 128 + m * 16 + fr;
                af[m] = *(const short8*)(Rb + row * 64 + ((fq ^ (row & 3)) << 4));
            }
            STAGE_B_H(tn, Wb, 0);
            BAR(); lgkm0();
            __builtin_amdgcn_s_setprio(1);
#pragma unroll
            for (int m = 4; m < 8; ++m)
#pragma unroll
                for (int n = 0; n < 4; ++n)
                    acc[m][n] = __builtin_amdgcn_mfma_f32_16x16x32_bf16(af[m], bf[n], acc[m][n], 0, 0, 0);
            __builtin_amdgcn_s_setprio(0);
            vmcnt4(); BAR();

            // ---- P3: kk1 af[0..3]+bf reads | stage Ah1(t+1) | MFMA m0-3 ----
#pragma unroll
            for (int m = 0; m < 4; ++m) {
                int row = wr * 128 + m * 16 + fr;
                af[m] = *(const short8*)(Rb + 16384 + row * 64 + ((fq ^ (row & 3)) << 4));
            }
#pragma unroll
            for (int n = 0; n < 4; ++n) {
                int row = wc * 64 + n * 16 + fr;
                bf[n] = *(const short8*)(Rb + 49152 + row * 64 + ((fq ^ (row & 3)) << 4));
            }
            STAGE_A_H(tn, Wb, 1);
            BAR(); lgkm0();
            __builtin_amdgcn_s_setprio(1);
#pragma unroll
            for (int m = 0; m < 4; ++m)
#pragma unroll
                for (int n = 0; n < 4; ++n)
                    acc[m][n] = __builtin_amdgcn_mfma_f32_16x16x32_bf16(af[m], bf[n], acc[m][n], 0, 0, 0);
            __builtin_amdgcn_s_setprio(0);
            BAR();

            // ---- P4: kk1 af[4..7] reads | stage Bh1(t+1) | MFMA m4-7 ----
#pragma unroll
            for (int m = 4; m < 8; ++m) {
                int row = wr * 128 + m * 16 + fr;
                af[m] = *(const short8*)(Rb + 16384 + row * 64 + ((fq ^ (row & 3)) << 4));
            }
            STAGE_B_H(tn, Wb, 1);
            BAR(); lgkm0();
            __builtin_amdgcn_s_setprio(1);
#pragma unroll
            for (int m = 4; m < 8; ++m)
#pragma unroll
                for (int n = 0; n < 4; ++n)
                    acc[m][n] = __builtin_amdgcn_mfma_f32_16x16x32_bf16(af[m], bf[n], acc[m][n], 0, 0, 0);
            __builtin_amdgcn_s_setprio(0);
            vmcnt4(); BAR();
        }
        asm volatile("s_waitcnt vmcnt(0)" ::: "memory");
        __syncthreads();
    } else {
        // MODE 1 fallback: packed nibbles, simple loop
        const int br  = tid >> 1;              // 0..255
        const int bc0 = (tid & 1) << 2;        // chunks bc0..bc0+3 (one half)
        const u32* pp2 = w2p + (size_t)(col0 + br) * (INTR / 8) + bc0;
        const size_t sBase = (size_t)(col0 + br) * GRP2;
        uint4 g2d;
        float sc, zz;

        auto LOADB = [&](int KS) {
            g2d = *(const uint4*)(pp2 + KS * 8);
            sc = s2[sBase + KS]; zz = z2[sBase + KS];
        };
        auto DEQWB = [&](char* buf) {
            u16* dB = (u16*)(buf + 32768);
            const float of = -zz * sc;
            const int h = bc0 >> 2;
            u32 ws[4] = {g2d.x, g2d.y, g2d.z, g2d.w};
#pragma unroll
            for (int j = 0; j < 4; ++j) {
                int p = j ^ (br & 3);
                *(uint4*)(&dB[h * 8192 + br * 32 + (p << 3)]) = dqw(ws[j], sc, of);
            }
        };

        LOADB(0);
        STAGE_A_H(0, smem, 0); STAGE_A_H(0, smem, 1);
        DEQWB(smem);
        __syncthreads();
        for (int ks = 0; ks < NK; ++ks) {
            const int nxt = ks + 1 < NK ? ks + 1 : NK - 1;
            const int cur = ks & 1;
            char* Wb = smem + (cur ^ 1) * 65536;
            const char* Rb = smem + cur * 65536;
            LOADB(nxt);
            STAGE_A_H(nxt, Wb, 0); STAGE_A_H(nxt, Wb, 1);
#pragma unroll
            for (int kk = 0; kk < 2; ++kk) {
                short8 af[8], bf[4];
#pragma unroll
                for (int m = 0; m < 8; ++m) {
                    int row = wr * 128 + m * 16 + fr;
                    af[m] = *(const short8*)(Rb + kk * 16384 + row * 64 + ((fq ^ (row & 3)) << 4));
                }
#pragma unroll
                for (int n = 0; n < 4; ++n) {
                    int row = wc * 64 + n * 16 + fr;
                    bf[n] = *(const short8*)(Rb + 32768 + kk * 16384 + row * 64 + ((fq ^ (row & 3)) << 4));
                }
#pragma unroll
                for (int m = 0; m < 8; ++m)
#pragma unroll
                    for (int n = 0; n < 4; ++n)
                        acc[m][n] = __builtin_amdgcn_mfma_f32_16x16x32_bf16(af[m], bf[n], acc[m][n], 0, 0, 0);
            }
            DEQWB(Wb);
            __syncthreads();
        }
    }

    // -- epilogue: fp32 tile through LDS, two 128-row passes (canonical out)
    float* sO = (float*)smem;   // [128][256] f32 = 128 KB
#pragma unroll
    for (int half = 0; half < 2; ++half) {
        if (half) __syncthreads();
        if (wr == half) {
#pragma unroll
            for (int m = 0; m < 8; ++m)
#pragma unroll
                for (int n = 0; n < 4; ++n)
#pragma unroll
                    for (int r = 0; r < 4; ++r) {
                        int lr = m * 16 + fq * 4 + r;
                        int lc = wc * 64 + n * 16 + fr;
                        int cs = ((((lc >> 2) ^ (lr & 7)) << 2) | (lc & 3));
                        sO[lr * 256 + cs] = acc[m][n][r];
                    }
        }
        __syncthreads();
#pragma unroll
        for (int it = 0; it < 16; ++it) {
            int idx = it * 512 + tid;
            int row = idx >> 6;
            int ch  = idx & 63;
            float4 v = ((const float4*)sO)[row * 64 + (ch ^ (row & 7))];
            *(float4*)(&out[(size_t)(row0 + half * 128 + row) * HID + col0 + (ch << 2)]) = v;
        }
    }
}

// ---- launcher --------------------------------------------------------------

extern "C" void kernel_launch(void* const* d_in, const int* in_sizes, int n_in,
                              void* d_out, int out_size, void* d_ws, size_t ws_size,
                              hipStream_t stream) {
    (void)in_sizes; (void)n_in; (void)out_size;

    const float* hs  = (const float*)d_in[0];
    const int*   w1q = (const int*)  d_in[1];
    const float* w1s = (const float*)d_in[2];
    const float* w1z = (const float*)d_in[3];
    const int*   w3q = (const int*)  d_in[4];
    const float* w3s = (const float*)d_in[5];
    const float* w3z = (const float*)d_in[6];
    const int*   w2q = (const int*)  d_in[7];
    const float* w2s = (const float*)d_in[8];
    const float* w2z = (const float*)d_in[9];
    float* out = (float*)d_out;

    const size_t NWRD  = (size_t)INTR * HID / 8;
    const size_t SZ_HSB  = (size_t)TOK * HID;
    const size_t SZ_HMID = (size_t)TOK * INTR;
    const size_t SZ_WB   = (size_t)INTR * HID;

    u16* hsb  = (u16*)d_ws;
    u16* hmid = hsb + SZ_HSB;
    u16* wb1  = hmid + SZ_HMID;
    u16* wb3  = wb1 + SZ_WB;
    u32* w1p  = (u32*)wb1;
    u32* w3p  = w1p + NWRD;
    u32* w2p  = w3p + NWRD;

    const size_t needF = (SZ_HSB + SZ_HMID + 2 * SZ_WB) * 2;
    const size_t needP = (SZ_HSB + SZ_HMID) * 2 + 3 * NWRD * 4;

    cvt_hs_kernel<<<(TOK * HID / 8) / 256, 256, 0, stream>>>(hs, hsb);

    dim3 g2(TOK / 256, INTR / 128);
    dim3 g3(TOK / 256, HID / 256);

    if (ws_size >= needF) {
        dqw_kernel<<<dim3(HID / 8 / 256, INTR), 256, 0, stream>>>(w1q, w1s, w1z, wb1, HID);
        dqw_kernel<<<dim3(HID / 8 / 256, INTR), 256, 0, stream>>>(w3q, w3s, w3z, wb3, HID);
        gateup_kernel<0><<<g2, 512, 0, stream>>>(hsb, wb1, wb3, nullptr, nullptr,
                                                 nullptr, nullptr, nullptr, nullptr, hmid);
        dqw_kernel<<<dim3(INTR / 8 / 256, HID), 256, 0, stream>>>(w2q, w2s, w2z, wb1, INTR);
        down_kernel<0><<<g3, 512, 0, stream>>>(hmid, wb1, nullptr, nullptr, nullptr, out);
    } else if (ws_size >= needP) {
        const int pgrid = (int)(NWRD / 256);
        pack_kernel<<<pgrid, 256, 0, stream>>>(w1q, w1p);
        pack_kernel<<<pgrid, 256, 0, stream>>>(w3q, w3p);
        pack_kernel<<<pgrid, 256, 0, stream>>>(w2q, w2p);
        gateup_kernel<1><<<g2, 512, 0, stream>>>(hsb, nullptr, nullptr, w1p, w3p,
                                                 w1s, w1z, w3s, w3z, hmid);
        down_kernel<1><<<g3, 512, 0, stream>>>(hmid, nullptr, w2p, w2s, w2z, out);
    }
}

// Round 10
// 1391.841 us; speedup vs baseline: 1.0502x; 1.0502x over previous
//
#include <hip/hip_runtime.h>
#include <hip/hip_bf16.h>
#include <stdint.h>

#define HID  4096
#define INTR 14336
#define GS   64
#define TOK  4096
#define GRP1 (HID / GS)
#define GRP2 (INTR / GS)

#define BK 64

typedef __attribute__((ext_vector_type(8))) short short8;  // 8 bf16
typedef __attribute__((ext_vector_type(4))) float f32x4;   // 16x16 MFMA acc
typedef unsigned short u16;
typedef unsigned int   u32;

// ---- helpers -------------------------------------------------------------

__device__ __forceinline__ u16 f2b(float x) {
    return __builtin_bit_cast(u16, __float2bfloat16(x));
}
__device__ __forceinline__ u32 pk2(float a, float b) {
    return (u32)f2b(a) | ((u32)f2b(b) << 16);
}
__device__ __forceinline__ u32 dq2(int ca, int cb, float s, float off) {
    return pk2(fmaf((float)ca, s, off), fmaf((float)cb, s, off));
}
__device__ __forceinline__ uint4 dqw(u32 w, float s, float off) {
    uint4 v;
    v.x = dq2((int)( w        & 15), (int)((w >>  4) & 15), s, off);
    v.y = dq2((int)((w >>  8) & 15), (int)((w >> 12) & 15), s, off);
    v.z = dq2((int)((w >> 16) & 15), (int)((w >> 20) & 15), s, off);
    v.w = dq2((int)((w >> 24) & 15), (int)( w >> 28       ), s, off);
    return v;
}
__device__ __forceinline__ void gload16(const void* g, void* l) {
    __builtin_amdgcn_global_load_lds(
        (const __attribute__((address_space(1))) void*)g,
        (__attribute__((address_space(3))) void*)l, 16, 0, 0);
}
__device__ __forceinline__ void vmcnt4() {
    asm volatile("s_waitcnt vmcnt(4)" ::: "memory");
}
__device__ __forceinline__ void lgkm0() {
    asm volatile("s_waitcnt lgkmcnt(0)" ::: "memory");
    __builtin_amdgcn_sched_barrier(0);
}
#define BAR() __builtin_amdgcn_s_barrier()

// ---- weight dequant: int32 codes -> bf16, PRE-SWIZZLE ---------------------
// position = (c & ~3) | ((c&3) ^ ((r>>1)&3))   [XOR within 32-elem K-half;
// (r>>1) so that 8 consecutive rows spread over (parity,chunk) = 8 slots]

__global__ void dqw_kernel(const int* __restrict__ q, const float* __restrict__ s,
                           const float* __restrict__ z, u16* __restrict__ o, int cols) {
    int c = blockIdx.x * blockDim.x + threadIdx.x;   // 8-elem chunk in row
    int r = blockIdx.y;
    int grp = cols >> 6;
    const int* src = q + (size_t)r * cols + ((size_t)c << 3);
    int4 a = *(const int4*)src;
    int4 b = *(const int4*)(src + 4);
    float sc = s[(size_t)r * grp + (c >> 3)];
    float zz = z[(size_t)r * grp + (c >> 3)];
    float of = -zz * sc;
    uint4 v;
    v.x = dq2(a.x, a.y, sc, of);
    v.y = dq2(a.z, a.w, sc, of);
    v.z = dq2(b.x, b.y, sc, of);
    v.w = dq2(b.z, b.w, sc, of);
    int cs = (c & ~3) | ((c & 3) ^ ((r >> 1) & 3));
    *(uint4*)(o + (size_t)r * cols + ((size_t)cs << 3)) = v;
}

// ---- repack (fallback): int32 -> 8x 4-bit nibbles per u32 -----------------

__global__ void pack_kernel(const int* __restrict__ q, u32* __restrict__ p) {
    int i = blockIdx.x * blockDim.x + threadIdx.x;
    const int4* s = (const int4*)q + (size_t)i * 2;
    int4 a = s[0], b = s[1];
    u32 w = (u32)(a.x & 15)        | ((u32)(a.y & 15) << 4)
          | ((u32)(a.z & 15) << 8) | ((u32)(a.w & 15) << 12)
          | ((u32)(b.x & 15) << 16)| ((u32)(b.y & 15) << 20)
          | ((u32)(b.z & 15) << 24)| ((u32)(b.w & 15) << 28);
    p[i] = w;
}

// ---- hs fp32 -> bf16, PRE-SWIZZLE -----------------------------------------

__global__ void cvt_hs_kernel(const float* __restrict__ x, u16* __restrict__ y) {
    int i = blockIdx.x * blockDim.x + threadIdx.x;
    int t = i >> 9;
    int c = i & 511;
    const float4* xp = (const float4*)x + (size_t)i * 2;
    float4 a = xp[0], b = xp[1];
    uint4 o;
    o.x = pk2(a.x, a.y); o.y = pk2(a.z, a.w);
    o.z = pk2(b.x, b.y); o.w = pk2(b.z, b.w);
    int cs = (c & ~3) | ((c & 3) ^ ((t >> 1) & 3));
    ((uint4*)y)[(size_t)t * 512 + cs] = o;
}

// swizzled chunk position for LDS reads: fq ^ ((row>>1)&3)
#define RPOS(row, fq) (((fq) ^ (((row) >> 1) & 3)) << 4)

// ---- kernel 2: fused gate+up dual GEMM + SiLU*mul -------------------------
// BM=256 BN=128 BK=64, 8 waves (4Mx2N), wave tile 64x64, 16x16x32 MFMA.
// LDS per buffer: A[2][256][32] 32K | B1[2][128][32] 16K | B3 16K. Dbuf 128K.
// MODE 0: 4-phase counted-vmcnt schedule. MODE 1: simple loop fallback.

template<int MODE>
__global__ __launch_bounds__(512) void gateup_kernel(
    const u16* __restrict__ hsb,
    const u16* __restrict__ w1b, const u16* __restrict__ w3b,
    const u32* __restrict__ w1p, const u32* __restrict__ w3p,
    const float* __restrict__ s1, const float* __restrict__ z1,
    const float* __restrict__ s3, const float* __restrict__ z3,
    u16* __restrict__ hout)
{
    __shared__ __align__(16) char smem[131072];

    const int tid  = threadIdx.x;
    const int row0 = blockIdx.x * 256;
    const int col0 = blockIdx.y * 128;

    const int l   = tid & 63;
    const int wid = tid >> 6;
    const int wr  = wid >> 1;
    const int wc  = wid & 1;
    const int fq  = l >> 4;
    const int fr  = l & 15;

    f32x4 accg[4][4];
    f32x4 accu[4][4];
#pragma unroll
    for (int m = 0; m < 4; ++m)
#pragma unroll
        for (int n = 0; n < 4; ++n) {
            accg[m][n] = (f32x4){0.f, 0.f, 0.f, 0.f};
            accu[m][n] = (f32x4){0.f, 0.f, 0.f, 0.f};
        }

    // DMA sources: lane covers row (l>>2), 16B chunk (l&3) -> 16 rows per 1KB
    const u16* aSrc  = hsb + (size_t)(row0 + (l >> 2)) * HID + ((l & 3) << 3);
    const u16* b1Src = w1b + (size_t)(col0 + (l >> 2)) * HID + ((l & 3) << 3);
    const u16* b3Src = w3b + (size_t)(col0 + (l >> 2)) * HID + ((l & 3) << 3);

    auto STAGE_A_H = [&](int KS, char* buf, int h) {
        const u16* s = aSrc + KS * 64 + h * 32;
#pragma unroll
        for (int i = 0; i < 2; ++i) {
            int blk = wid * 2 + i;
            gload16(s + (size_t)(blk * 16) * HID, buf + h * 16384 + (blk << 10));
        }
    };
    auto STAGE_B_H = [&](int KS, char* buf, int h) {
        gload16(b1Src + KS * 64 + h * 32 + (size_t)(wid * 16) * HID,
                buf + 32768 + h * 8192 + (wid << 10));
        gload16(b3Src + KS * 64 + h * 32 + (size_t)(wid * 16) * HID,
                buf + 49152 + h * 8192 + (wid << 10));
    };

    const int NK = HID / BK;   // 64

    if constexpr (MODE == 0) {
        STAGE_A_H(0, smem, 0);
        STAGE_B_H(0, smem, 0);
        STAGE_A_H(0, smem, 1);
        STAGE_B_H(0, smem, 1);
        vmcnt4(); BAR();

        for (int t = 0; t < NK; ++t) {
            const int cur = t & 1;
            const char* Rb = smem + cur * 65536;
            char* Wb = smem + (cur ^ 1) * 65536;
            const int tn = (t + 1 < NK) ? t + 1 : NK - 1;
            short8 af[4], b1f[4], b3f[4];

            // ---- P1: kk0 A+B1 reads | stage Ah0(t+1) | MFMA g0 ----
#pragma unroll
            for (int m = 0; m < 4; ++m) {
                int row = wr * 64 + m * 16 + fr;
                af[m] = *(const short8*)(Rb + row * 64 + RPOS(row, fq));
            }
#pragma unroll
            for (int n = 0; n < 4; ++n) {
                int row = wc * 64 + n * 16 + fr;
                b1f[n] = *(const short8*)(Rb + 32768 + row * 64 + RPOS(row, fq));
            }
            STAGE_A_H(tn, Wb, 0);
            BAR(); lgkm0();
            __builtin_amdgcn_s_setprio(1);
#pragma unroll
            for (int m = 0; m < 4; ++m)
#pragma unroll
                for (int n = 0; n < 4; ++n)
                    accg[m][n] = __builtin_amdgcn_mfma_f32_16x16x32_bf16(af[m], b1f[n], accg[m][n], 0, 0, 0);
            __builtin_amdgcn_s_setprio(0);
            BAR();

            // ---- P2: kk0 B3 reads | stage Bh0(t+1) | MFMA u0 | vmcnt(4) ----
#pragma unroll
            for (int n = 0; n < 4; ++n) {
                int row = wc * 64 + n * 16 + fr;
                b3f[n] = *(const short8*)(Rb + 49152 + row * 64 + RPOS(row, fq));
            }
            STAGE_B_H(tn, Wb, 0);
            BAR(); lgkm0();
            __builtin_amdgcn_s_setprio(1);
#pragma unroll
            for (int m = 0; m < 4; ++m)
#pragma unroll
                for (int n = 0; n < 4; ++n)
                    accu[m][n] = __builtin_amdgcn_mfma_f32_16x16x32_bf16(af[m], b3f[n], accu[m][n], 0, 0, 0);
            __builtin_amdgcn_s_setprio(0);
            vmcnt4(); BAR();      // h1(t) ready

            // ---- P3: kk1 A+B1 reads | stage Ah1(t+1) | MFMA g1 ----
#pragma unroll
            for (int m = 0; m < 4; ++m) {
                int row = wr * 64 + m * 16 + fr;
                af[m] = *(const short8*)(Rb + 16384 + row * 64 + RPOS(row, fq));
            }
#pragma unroll
            for (int n = 0; n < 4; ++n) {
                int row = wc * 64 + n * 16 + fr;
                b1f[n] = *(const short8*)(Rb + 40960 + row * 64 + RPOS(row, fq));
            }
            STAGE_A_H(tn, Wb, 1);
            BAR(); lgkm0();
            __builtin_amdgcn_s_setprio(1);
#pragma unroll
            for (int m = 0; m < 4; ++m)
#pragma unroll
                for (int n = 0; n < 4; ++n)
                    accg[m][n] = __builtin_amdgcn_mfma_f32_16x16x32_bf16(af[m], b1f[n], accg[m][n], 0, 0, 0);
            __builtin_amdgcn_s_setprio(0);
            BAR();

            // ---- P4: kk1 B3 reads | stage Bh1(t+1) | MFMA u1 | vmcnt(4) ----
#pragma unroll
            for (int n = 0; n < 4; ++n) {
                int row = wc * 64 + n * 16 + fr;
                b3f[n] = *(const short8*)(Rb + 57344 + row * 64 + RPOS(row, fq));
            }
            STAGE_B_H(tn, Wb, 1);
            BAR(); lgkm0();
            __builtin_amdgcn_s_setprio(1);
#pragma unroll
            for (int m = 0; m < 4; ++m)
#pragma unroll
                for (int n = 0; n < 4; ++n)
                    accu[m][n] = __builtin_amdgcn_mfma_f32_16x16x32_bf16(af[m], b3f[n], accu[m][n], 0, 0, 0);
            __builtin_amdgcn_s_setprio(0);
            vmcnt4(); BAR();      // h0(t+1) ready
        }
        asm volatile("s_waitcnt vmcnt(0)" ::: "memory");
        __syncthreads();
    } else {
        // MODE 1 fallback: packed nibbles, simple double-buffer loop
        const int br  = tid >> 2;
        const int bc  = tid & 3;
        const u32* pp1 = w1p + (size_t)(col0 + br) * (HID / 8) + (bc << 1);
        const u32* pp3 = w3p + (size_t)(col0 + br) * (HID / 8) + (bc << 1);
        const size_t sBase = (size_t)(col0 + br) * GRP1;
        uint2 g1, g3;
        float sc1, zz1, sc3, zz3;

        auto LOADB = [&](int KS) {
            g1 = *(const uint2*)(pp1 + KS * 8);
            g3 = *(const uint2*)(pp3 + KS * 8);
            sc1 = s1[sBase + KS]; zz1 = z1[sBase + KS];
            sc3 = s3[sBase + KS]; zz3 = z3[sBase + KS];
        };
        auto DEQWB = [&](char* buf) {
            u16* dB1 = (u16*)(buf + 32768);
            u16* dB3 = (u16*)(buf + 49152);
            const float of1 = -zz1 * sc1;
            const float of3 = -zz3 * sc3;
            int c0 = bc << 1;
            int x  = (br >> 1) & 3;
            int p0 = (c0 & 3) ^ x;
            int p1 = ((c0 + 1) & 3) ^ x;
            int h  = bc >> 1;
            *(uint4*)(&dB1[h * 4096 + br * 32 + (p0 << 3)]) = dqw(g1.x, sc1, of1);
            *(uint4*)(&dB1[h * 4096 + br * 32 + (p1 << 3)]) = dqw(g1.y, sc1, of1);
            *(uint4*)(&dB3[h * 4096 + br * 32 + (p0 << 3)]) = dqw(g3.x, sc3, of3);
            *(uint4*)(&dB3[h * 4096 + br * 32 + (p1 << 3)]) = dqw(g3.y, sc3, of3);
        };

        LOADB(0);
        STAGE_A_H(0, smem, 0); STAGE_A_H(0, smem, 1);
        DEQWB(smem);
        __syncthreads();
        for (int ks = 0; ks < NK; ++ks) {
            const int nxt = ks + 1 < NK ? ks + 1 : NK - 1;
            const int cur = ks & 1;
            char* Wb = smem + (cur ^ 1) * 65536;
            const char* Rb = smem + cur * 65536;
            LOADB(nxt);
            STAGE_A_H(nxt, Wb, 0); STAGE_A_H(nxt, Wb, 1);
#pragma unroll
            for (int kk = 0; kk < 2; ++kk) {
                short8 af[4], b1f[4], b3f[4];
#pragma unroll
                for (int m = 0; m < 4; ++m) {
                    int row = wr * 64 + m * 16 + fr;
                    af[m] = *(const short8*)(Rb + kk * 16384 + row * 64 + RPOS(row, fq));
                }
#pragma unroll
                for (int n = 0; n < 4; ++n) {
                    int row = wc * 64 + n * 16 + fr;
                    int off = row * 64 + RPOS(row, fq);
                    b1f[n] = *(const short8*)(Rb + 32768 + kk * 8192 + off);
                    b3f[n] = *(const short8*)(Rb + 49152 + kk * 8192 + off);
                }
#pragma unroll
                for (int m = 0; m < 4; ++m)
#pragma unroll
                    for (int n = 0; n < 4; ++n) {
                        accg[m][n] = __builtin_amdgcn_mfma_f32_16x16x32_bf16(af[m], b1f[n], accg[m][n], 0, 0, 0);
                        accu[m][n] = __builtin_amdgcn_mfma_f32_16x16x32_bf16(af[m], b3f[n], accu[m][n], 0, 0, 0);
                    }
            }
            DEQWB(Wb);
            __syncthreads();
        }
    }

    // -- epilogue: silu(g)*u -> LDS (pre-swizzled positions) -> store
    u16* sO = (u16*)smem;    // [256][128] bf16 = 64 KB
#pragma unroll
    for (int m = 0; m < 4; ++m)
#pragma unroll
        for (int n = 0; n < 4; ++n)
#pragma unroll
            for (int r = 0; r < 4; ++r) {
                int lr = wr * 64 + m * 16 + fq * 4 + r;
                int lc = wc * 64 + n * 16 + fr;
                float g = accg[m][n][r];
                float u = accu[m][n][r];
                float hv = (g / (1.0f + __expf(-g))) * u;
                int c  = lc >> 3;
                int cs = (c & ~3) | ((c & 3) ^ ((lr >> 1) & 3));
                sO[lr * 128 + (cs << 3) + (lc & 7)] = f2b(hv);
            }
    __syncthreads();
#pragma unroll
    for (int it = 0; it < 8; ++it) {
        int idx = it * 512 + tid;          // 16B units
        int row = idx >> 4;
        int cu  = idx & 15;
        uint4 v = ((const uint4*)sO)[row * 16 + cu];
        *(uint4*)(&hout[(size_t)(row0 + row) * INTR + col0 + (cu << 3)]) = v;
    }
}

// ---- kernel 3: down proj --------------------------------------------------
// BM=256 BN=256 BK=64, 8 waves (2Mx4N), wave tile 128x64.

template<int MODE>
__global__ __launch_bounds__(512) void down_kernel(
    const u16* __restrict__ hb,
    const u16* __restrict__ w2b, const u32* __restrict__ w2p,
    const float* __restrict__ s2, const float* __restrict__ z2,
    float* __restrict__ out)
{
    __shared__ __align__(16) char smem[131072];

    const int tid  = threadIdx.x;
    const int row0 = blockIdx.x * 256;
    const int col0 = blockIdx.y * 256;

    const int l   = tid & 63;
    const int wid = tid >> 6;
    const int wr  = wid >> 2;
    const int wc  = wid & 3;
    const int fq  = l >> 4;
    const int fr  = l & 15;

    f32x4 acc[8][4];
#pragma unroll
    for (int m = 0; m < 8; ++m)
#pragma unroll
        for (int n = 0; n < 4; ++n)
            acc[m][n] = (f32x4){0.f, 0.f, 0.f, 0.f};

    const u16* aSrc = hb  + (size_t)(row0 + (l >> 2)) * INTR + ((l & 3) << 3);
    const u16* bSrc = w2b + (size_t)(col0 + (l >> 2)) * INTR + ((l & 3) << 3);

    auto STAGE_A_H = [&](int KS, char* buf, int h) {
        const u16* s = aSrc + KS * 64 + h * 32;
#pragma unroll
        for (int i = 0; i < 2; ++i) {
            int blk = wid * 2 + i;
            gload16(s + (size_t)(blk * 16) * INTR, buf + h * 16384 + (blk << 10));
        }
    };
    auto STAGE_B_H = [&](int KS, char* buf, int h) {
        const u16* s = bSrc + KS * 64 + h * 32;
#pragma unroll
        for (int i = 0; i < 2; ++i) {
            int blk = wid * 2 + i;
            gload16(s + (size_t)(blk * 16) * INTR, buf + 32768 + h * 16384 + (blk << 10));
        }
    };

    const int NK = INTR / BK;   // 224

    if constexpr (MODE == 0) {
        STAGE_A_H(0, smem, 0);
        STAGE_B_H(0, smem, 0);
        STAGE_A_H(0, smem, 1);
        STAGE_B_H(0, smem, 1);
        vmcnt4(); BAR();

        for (int t = 0; t < NK; ++t) {
            const int cur = t & 1;
            const char* Rb = smem + cur * 65536;
            char* Wb = smem + (cur ^ 1) * 65536;
            const int tn = (t + 1 < NK) ? t + 1 : NK - 1;
            short8 af[8], bf[4];

            // ---- P1 ----
#pragma unroll
            for (int m = 0; m < 4; ++m) {
                int row = wr * 128 + m * 16 + fr;
                af[m] = *(const short8*)(Rb + row * 64 + RPOS(row, fq));
            }
#pragma unroll
            for (int n = 0; n < 4; ++n) {
                int row = wc * 64 + n * 16 + fr;
                bf[n] = *(const short8*)(Rb + 32768 + row * 64 + RPOS(row, fq));
            }
            STAGE_A_H(tn, Wb, 0);
            BAR(); lgkm0();
            __builtin_amdgcn_s_setprio(1);
#pragma unroll
            for (int m = 0; m < 4; ++m)
#pragma unroll
                for (int n = 0; n < 4; ++n)
                    acc[m][n] = __builtin_amdgcn_mfma_f32_16x16x32_bf16(af[m], bf[n], acc[m][n], 0, 0, 0);
            __builtin_amdgcn_s_setprio(0);
            BAR();

            // ---- P2 ----
#pragma unroll
            for (int m = 4; m < 8; ++m) {
                int row = wr * 128 + m * 16 + fr;
                af[m] = *(const short8*)(Rb + row * 64 + RPOS(row, fq));
            }
            STAGE_B_H(tn, Wb, 0);
            BAR(); lgkm0();
            __builtin_amdgcn_s_setprio(1);
#pragma unroll
            for (int m = 4; m < 8; ++m)
#pragma unroll
                for (int n = 0; n < 4; ++n)
                    acc[m][n] = __builtin_amdgcn_mfma_f32_16x16x32_bf16(af[m], bf[n], acc[m][n], 0, 0, 0);
            __builtin_amdgcn_s_setprio(0);
            vmcnt4(); BAR();

            // ---- P3 ----
#pragma unroll
            for (int m = 0; m < 4; ++m) {
                int row = wr * 128 + m * 16 + fr;
                af[m] = *(const short8*)(Rb + 16384 + row * 64 + RPOS(row, fq));
            }
#pragma unroll
            for (int n = 0; n < 4; ++n) {
                int row = wc * 64 + n * 16 + fr;
                bf[n] = *(const short8*)(Rb + 49152 + row * 64 + RPOS(row, fq));
            }
            STAGE_A_H(tn, Wb, 1);
            BAR(); lgkm0();
            __builtin_amdgcn_s_setprio(1);
#pragma unroll
            for (int m = 0; m < 4; ++m)
#pragma unroll
                for (int n = 0; n < 4; ++n)
                    acc[m][n] = __builtin_amdgcn_mfma_f32_16x16x32_bf16(af[m], bf[n], acc[m][n], 0, 0, 0);
            __builtin_amdgcn_s_setprio(0);
            BAR();

            // ---- P4 ----
#pragma unroll
            for (int m = 4; m < 8; ++m) {
                int row = wr * 128 + m * 16 + fr;
                af[m] = *(const short8*)(Rb + 16384 + row * 64 + RPOS(row, fq));
            }
            STAGE_B_H(tn, Wb, 1);
            BAR(); lgkm0();
            __builtin_amdgcn_s_setprio(1);
#pragma unroll
            for (int m = 4; m < 8; ++m)
#pragma unroll
                for (int n = 0; n < 4; ++n)
                    acc[m][n] = __builtin_amdgcn_mfma_f32_16x16x32_bf16(af[m], bf[n], acc[m][n], 0, 0, 0);
            __builtin_amdgcn_s_setprio(0);
            vmcnt4(); BAR();
        }
        asm volatile("s_waitcnt vmcnt(0)" ::: "memory");
        __syncthreads();
    } else {
        // MODE 1 fallback
        const int br  = tid >> 1;
        const int bc0 = (tid & 1) << 2;
        const u32* pp2 = w2p + (size_t)(col0 + br) * (INTR / 8) + bc0;
        const size_t sBase = (size_t)(col0 + br) * GRP2;
        uint4 g2d;
        float sc, zz;

        auto LOADB = [&](int KS) {
            g2d = *(const uint4*)(pp2 + KS * 8);
            sc = s2[sBase + KS]; zz = z2[sBase + KS];
        };
        auto DEQWB = [&](char* buf) {
            u16* dB = (u16*)(buf + 32768);
            const float of = -zz * sc;
            const int h = bc0 >> 2;
            const int x = (br >> 1) & 3;
            u32 ws[4] = {g2d.x, g2d.y, g2d.z, g2d.w};
#pragma unroll
            for (int j = 0; j < 4; ++j) {
                int p = j ^ x;
                *(uint4*)(&dB[h * 8192 + br * 32 + (p << 3)]) = dqw(ws[j], sc, of);
            }
        };

        LOADB(0);
        STAGE_A_H(0, smem, 0); STAGE_A_H(0, smem, 1);
        DEQWB(smem);
        __syncthreads();
        for (int ks = 0; ks < NK; ++ks) {
            const int nxt = ks + 1 < NK ? ks + 1 : NK - 1;
            const int cur = ks & 1;
            char* Wb = smem + (cur ^ 1) * 65536;
            const char* Rb = smem + cur * 65536;
            LOADB(nxt);
            STAGE_A_H(nxt, Wb, 0); STAGE_A_H(nxt, Wb, 1);
#pragma unroll
            for (int kk = 0; kk < 2; ++kk) {
                short8 af[8], bf[4];
#pragma unroll
                for (int m = 0; m < 8; ++m) {
                    int row = wr * 128 + m * 16 + fr;
                    af[m] = *(const short8*)(Rb + kk * 16384 + row * 64 + RPOS(row, fq));
                }
#pragma unroll
                for (int n = 0; n < 4; ++n) {
                    int row = wc * 64 + n * 16 + fr;
                    bf[n] = *(const short8*)(Rb + 32768 + kk * 16384 + row * 64 + RPOS(row, fq));
                }
#pragma unroll
                for (int m = 0; m < 8; ++m)
#pragma unroll
                    for (int n = 0; n < 4; ++n)
                        acc[m][n] = __builtin_amdgcn_mfma_f32_16x16x32_bf16(af[m], bf[n], acc[m][n], 0, 0, 0);
            }
            DEQWB(Wb);
            __syncthreads();
        }
    }

    // -- epilogue: fp32 tile through LDS, two 128-row passes (canonical out)
    float* sO = (float*)smem;   // [128][256] f32 = 128 KB
#pragma unroll
    for (int half = 0; half < 2; ++half) {
        if (half) __syncthreads();
        if (wr == half) {
#pragma unroll
            for (int m = 0; m < 8; ++m)
#pragma unroll
                for (int n = 0; n < 4; ++n)
#pragma unroll
                    for (int r = 0; r < 4; ++r) {
                        int lr = m * 16 + fq * 4 + r;
                        int lc = wc * 64 + n * 16 + fr;
                        int cs = ((((lc >> 2) ^ (lr & 7)) << 2) | (lc & 3));
                        sO[lr * 256 + cs] = acc[m][n][r];
                    }
        }
        __syncthreads();
#pragma unroll
        for (int it = 0; it < 16; ++it) {
            int idx = it * 512 + tid;
            int row = idx >> 6;
            int ch  = idx & 63;
            float4 v = ((const float4*)sO)[row * 64 + (ch ^ (row & 7))];
            *(float4*)(&out[(size_t)(row0 + half * 128 + row) * HID + col0 + (ch << 2)]) = v;
        }
    }
}

// ---- launcher --------------------------------------------------------------

extern "C" void kernel_launch(void* const* d_in, const int* in_sizes, int n_in,
                              void* d_out, int out_size, void* d_ws, size_t ws_size,
                              hipStream_t stream) {
    (void)in_sizes; (void)n_in; (void)out_size;

    const float* hs  = (const float*)d_in[0];
    const int*   w1q = (const int*)  d_in[1];
    const float* w1s = (const float*)d_in[2];
    const float* w1z = (const float*)d_in[3];
    const int*   w3q = (const int*)  d_in[4];
    const float* w3s = (const float*)d_in[5];
    const float* w3z = (const float*)d_in[6];
    const int*   w2q = (const int*)  d_in[7];
    const float* w2s = (const float*)d_in[8];
    const float* w2z = (const float*)d_in[9];
    float* out = (float*)d_out;

    const size_t NWRD  = (size_t)INTR * HID / 8;
    const size_t SZ_HSB  = (size_t)TOK * HID;
    const size_t SZ_HMID = (size_t)TOK * INTR;
    const size_t SZ_WB   = (size_t)INTR * HID;

    u16* hsb  = (u16*)d_ws;
    u16* hmid = hsb + SZ_HSB;
    u16* wb1  = hmid + SZ_HMID;
    u16* wb3  = wb1 + SZ_WB;
    u32* w1p  = (u32*)wb1;
    u32* w3p  = w1p + NWRD;
    u32* w2p  = w3p + NWRD;

    const size_t needF = (SZ_HSB + SZ_HMID + 2 * SZ_WB) * 2;
    const size_t needP = (SZ_HSB + SZ_HMID) * 2 + 3 * NWRD * 4;

    cvt_hs_kernel<<<(TOK * HID / 8) / 256, 256, 0, stream>>>(hs, hsb);

    dim3 g2(TOK / 256, INTR / 128);
    dim3 g3(TOK / 256, HID / 256);

    if (ws_size >= needF) {
        dqw_kernel<<<dim3(HID / 8 / 256, INTR), 256, 0, stream>>>(w1q, w1s, w1z, wb1, HID);
        dqw_kernel<<<dim3(HID / 8 / 256, INTR), 256, 0, stream>>>(w3q, w3s, w3z, wb3, HID);
        gateup_kernel<0><<<g2, 512, 0, stream>>>(hsb, wb1, wb3, nullptr, nullptr,
                                                 nullptr, nullptr, nullptr, nullptr, hmid);
        dqw_kernel<<<dim3(INTR / 8 / 256, HID), 256, 0, stream>>>(w2q, w2s, w2z, wb1, INTR);
        down_kernel<0><<<g3, 512, 0, stream>>>(hmid, wb1, nullptr, nullptr, nullptr, out);
    } else if (ws_size >= needP) {
        const int pgrid = (int)(NWRD / 256);
        pack_kernel<<<pgrid, 256, 0, stream>>>(w1q, w1p);
        pack_kernel<<<pgrid, 256, 0, stream>>>(w3q, w3p);
        pack_kernel<<<pgrid, 256, 0, stream>>>(w2q, w2p);
        gateup_kernel<1><<<g2, 512, 0, stream>>>(hsb, nullptr, nullptr, w1p, w3p,
                                                 w1s, w1z, w3s, w3z, hmid);
        down_kernel<1><<<g3, 512, 0, stream>>>(hmid, nullptr, w2p, w2s, w2z, out);
    }
}